// Round 3
// baseline (525.485 us; speedup 1.0000x reference)
//
#include <hip/hip_runtime.h>
#include <hip/hip_bf16.h>

// hierarch_sep_loss: preds [2, N, 100] fp32 probs, labs [2, N] int, cen [2, N] int
// out[0] = sum over mods of:
//   (n_u/N) * (-sum_{cen==0} log(p[i,lab_i]+EPS) / max(1,n_u))
// + (n_c/N) * (-sum_{cen==1} log(sum_{j>lab0_i} p[i,j]+EPS) / max(1,n_c)) * 0.5
//
// R8 post-mortem: batch-4 MLP restructure neutral (481.6 vs 480.5) -> not
// latency-bound. Model: gather fetches ~400MB of HBM *granules* anyway
// (128-256B per scattered row touch) at the 2.9 TB/s scatter plateau
// (= ~140us). R7's "stream" was ALSO a scatter at wave level (16 disjoint
// 64B segments per instruction, group-strided) -> 1.8 TB/s.
// R9: same ~400MB, but LANE-LINEAR (m13 copy pattern: 64 lanes x 16B =
// contiguous 1KB per wave instruction, 6.29 TB/s verified achievable).
//  - block owns 256-row tile (100KB contiguous preds)
//  - Phase A: coalesced descriptors -> per-row [lo,hi] in LDS
//      uncensored: lo=hi=lab ; censored: lo=t1, hi=99 (exact suffix)
//  - Phase B: thread t streams float4 f=t+256*it; masked 4-elem partial
//      (lo/hi via broadcast LDS read); write sh_part[f] (stride-1, free)
//  - Phase C: thread t sums its row's 25 partials (stride-25, gcd(25,32)=1
//      -> conflict-free), one logf, accumulate per (mod, cen).
// LDS 28.7KB -> 5 blocks/CU, 20 waves/CU.

#define HSL_EPS 1e-10f
#define NBLK 2048
#define TILE 256
#define F4R  25   // float4s per row (B=100)

__global__ __launch_bounds__(256, 4) void hsl_main(
    const float* __restrict__ preds,
    const int*   __restrict__ labs,
    const int*   __restrict__ cen,
    double*       __restrict__ bsums,  // [4][NBLK] per-block partials
    unsigned int* __restrict__ bcnts,  // [4][NBLK]
    long long N)
{
    const long long R = 2LL * N;
    const long long ntiles = (R + TILE - 1) / TILE;
    const int t = threadIdx.x;

    double usum[2] = {0.0, 0.0};
    double csum[2] = {0.0, 0.0};
    unsigned int ucnt[2] = {0u, 0u};
    unsigned int ccnt[2] = {0u, 0u};

    __shared__ int   sh_lo[TILE];
    __shared__ int   sh_hi[TILE];
    __shared__ int   sh_c [TILE];
    __shared__ float sh_part[TILE * F4R];   // 25600 B

    for (long long tb = blockIdx.x; tb < ntiles; tb += gridDim.x) {
        const long long r0 = tb * (long long)TILE;
        const int nrow = (int)((R - r0 < (long long)TILE) ? (R - r0) : (long long)TILE);

        // ---- Phase A: coalesced descriptor loads -> [lo,hi] per row ----
        if (t < nrow) {
            const long long r = r0 + t;
            const int c    = cen[r];
            const int lab  = labs[r];
            const int lab0 = (r >= N) ? labs[r - N] : lab;  // mod0: labs0==lab
            sh_c[t]  = c;
            sh_lo[t] = c ? (lab0 + 1) : lab;   // t1 in [1,100]; t1=100 -> empty -> 0
            sh_hi[t] = c ? 99 : lab;
        }
        __syncthreads();

        // ---- Phase B: lane-linear stream (1KB contiguous per wave instr) ----
        const float4* tp4 = (const float4*)(preds + r0 * 100);
        if (nrow == TILE) {
            #pragma unroll 5
            for (int it = 0; it < F4R; ++it) {
                const int f = t + it * 256;
                const float4 v = tp4[f];
                const unsigned row = (unsigned)f / (unsigned)F4R;
                const int j0 = (f - (int)row * F4R) * 4;
                const int lo = sh_lo[row];
                const int hi = sh_hi[row];
                float s = 0.0f;
                s += (j0     >= lo && j0     <= hi) ? v.x : 0.0f;
                s += (j0 + 1 >= lo && j0 + 1 <= hi) ? v.y : 0.0f;
                s += (j0 + 2 >= lo && j0 + 2 <= hi) ? v.z : 0.0f;
                s += (j0 + 3 >= lo && j0 + 3 <= hi) ? v.w : 0.0f;
                sh_part[f] = s;
            }
        } else {
            const int nf4 = nrow * F4R;
            for (int f = t; f < nf4; f += 256) {
                const float4 v = tp4[f];
                const unsigned row = (unsigned)f / (unsigned)F4R;
                const int j0 = (f - (int)row * F4R) * 4;
                const int lo = sh_lo[row];
                const int hi = sh_hi[row];
                float s = 0.0f;
                s += (j0     >= lo && j0     <= hi) ? v.x : 0.0f;
                s += (j0 + 1 >= lo && j0 + 1 <= hi) ? v.y : 0.0f;
                s += (j0 + 2 >= lo && j0 + 2 <= hi) ? v.z : 0.0f;
                s += (j0 + 3 >= lo && j0 + 3 <= hi) ? v.w : 0.0f;
                sh_part[f] = s;
            }
        }
        __syncthreads();

        // ---- Phase C: per-row reduce (stride-25 LDS, conflict-free) + logf ----
        if (t < nrow) {
            float sum = 0.0f;
            #pragma unroll
            for (int k = 0; k < F4R; ++k) sum += sh_part[t * F4R + k];
            const long long r = r0 + t;
            const int m = (r >= N) ? 1 : 0;
            const double lg = (double)logf(sum + HSL_EPS);
            if (sh_c[t] == 0) { usum[m] += lg; ucnt[m]++; }
            else              { csum[m] += lg; ccnt[m]++; }
        }
        __syncthreads();   // before next tile's Phase A overwrites LDS
    }

    // ---- wave shuffle reduction -> block LDS -> one plain store per block ----
    #pragma unroll
    for (int off = 32; off > 0; off >>= 1) {
        usum[0] += __shfl_down(usum[0], off, 64);
        csum[0] += __shfl_down(csum[0], off, 64);
        usum[1] += __shfl_down(usum[1], off, 64);
        csum[1] += __shfl_down(csum[1], off, 64);
        ucnt[0] += __shfl_down(ucnt[0], off, 64);
        ccnt[0] += __shfl_down(ccnt[0], off, 64);
        ucnt[1] += __shfl_down(ucnt[1], off, 64);
        ccnt[1] += __shfl_down(ccnt[1], off, 64);
    }

    __shared__ double sh_sums[4][4];
    __shared__ unsigned int sh_cnts[4][4];
    const int waveInBlk = threadIdx.x >> 6;
    const int lane = threadIdx.x & 63;
    if (lane == 0) {
        sh_sums[waveInBlk][0] = usum[0]; sh_sums[waveInBlk][1] = csum[0];
        sh_sums[waveInBlk][2] = usum[1]; sh_sums[waveInBlk][3] = csum[1];
        sh_cnts[waveInBlk][0] = ucnt[0]; sh_cnts[waveInBlk][1] = ccnt[0];
        sh_cnts[waveInBlk][2] = ucnt[1]; sh_cnts[waveInBlk][3] = ccnt[1];
    }
    __syncthreads();
    if (threadIdx.x < 4) {
        const int slot = threadIdx.x;
        double s = 0.0; unsigned int k = 0u;
        for (int w = 0; w < 4; ++w) { s += sh_sums[w][slot]; k += sh_cnts[w][slot]; }
        bsums[slot * NBLK + blockIdx.x] = s;
        bcnts[slot * NBLK + blockIdx.x] = k;
    }
}

__global__ __launch_bounds__(256) void hsl_final(
    const double* __restrict__ bsums,
    const unsigned int* __restrict__ bcnts,
    float* __restrict__ out, long long N, int nblk)
{
    double s[4] = {0.0, 0.0, 0.0, 0.0};
    double kc[4] = {0.0, 0.0, 0.0, 0.0};
    for (int b = threadIdx.x; b < nblk; b += 256) {
        #pragma unroll
        for (int slot = 0; slot < 4; ++slot) {
            s[slot]  += bsums[slot * nblk + b];
            kc[slot] += (double)bcnts[slot * nblk + b];
        }
    }

    #pragma unroll
    for (int off = 32; off > 0; off >>= 1) {
        #pragma unroll
        for (int slot = 0; slot < 4; ++slot) {
            s[slot]  += __shfl_down(s[slot],  off, 64);
            kc[slot] += __shfl_down(kc[slot], off, 64);
        }
    }

    __shared__ double sh[4][8];
    const int waveInBlk = threadIdx.x >> 6;
    const int lane = threadIdx.x & 63;
    if (lane == 0) {
        #pragma unroll
        for (int slot = 0; slot < 4; ++slot) {
            sh[waveInBlk][slot]     = s[slot];
            sh[waveInBlk][4 + slot] = kc[slot];
        }
    }
    __syncthreads();
    if (threadIdx.x == 0) {
        double fs[4], fk[4];
        #pragma unroll
        for (int slot = 0; slot < 4; ++slot) {
            fs[slot] = sh[0][slot] + sh[1][slot] + sh[2][slot] + sh[3][slot];
            fk[slot] = sh[0][4+slot] + sh[1][4+slot] + sh[2][4+slot] + sh[3][4+slot];
        }
        float total = 0.0f;
        const float n = (float)N;
        for (int m = 0; m < 2; ++m) {
            const float nu = (float)fk[2 * m + 0];
            const float nc = (float)fk[2 * m + 1];
            const float us = (float)fs[2 * m + 0];
            const float cs = (float)fs[2 * m + 1];
            const float uncen_loss = -us / fmaxf(1.0f, nu);
            const float cen_loss   = -cs / fmaxf(1.0f, nc);
            total += (nu / n) * uncen_loss + (nc / n) * cen_loss * 0.5f;
        }
        out[0] = total;
    }
}

extern "C" void kernel_launch(void* const* d_in, const int* in_sizes, int n_in,
                              void* d_out, int out_size, void* d_ws, size_t ws_size,
                              hipStream_t stream)
{
    const float* preds = (const float*)d_in[0];
    const int*   labs  = (const int*)d_in[1];
    const int*   cen   = (const int*)d_in[2];
    float* out = (float*)d_out;

    const long long N = (long long)(in_sizes[1] / 2);   // labs flat = 2*N; B=100 hardcoded

    double*       bsums = (double*)d_ws;
    unsigned int* bcnts = (unsigned int*)((char*)d_ws + (size_t)4 * NBLK * sizeof(double));

    hsl_main<<<NBLK, 256, 0, stream>>>(preds, labs, cen, bsums, bcnts, N);
    hsl_final<<<1, 256, 0, stream>>>(bsums, bcnts, out, N, NBLK);
}

// Round 4
// 495.378 us; speedup vs baseline: 1.0608x; 1.0608x over previous
//
#include <hip/hip_runtime.h>
#include <hip/hip_bf16.h>

// hierarch_sep_loss: preds [2, N, 100] fp32 probs, labs [2, N] int, cen [2, N] int
// out[0] = sum over mods of:
//   (n_u/N) * (-sum_{cen==0} log(p[i,lab_i]+EPS) / max(1,n_u))
// + (n_c/N) * (-sum_{cen==1} log(sum_{j>lab0_i} p[i,j]+EPS) / max(1,n_c)) * 0.5
//
// Cross-round model (R6=480.5 base, R7 +85, R8 +1, R9 +45): read path
// plateaus ~3 TB/s for ANY structure (m13's 6.29 TB/s is copy = rd+wr;
// fills are write-only), and the R6 gather already pulls ~256B of granule
// per 400B row -> every variant is traffic-bound at ~110-140us base; the
// deltas were pure VALU/LDS/coalescing overhead ON TOP. So: keep R6's
// minimal-granule access, strip the overhead above the traffic floor.
// R10: WAVE-TRANSPOSED gather. Lane i owns row base+i.
//  - descriptors: 3 fully-coalesced loads (cen/labs[+labs0 for mod1])
//  - unified per-lane masked sum over [lo,hi], <=13 predicated float4s:
//      uncen: lo=hi=lab (1 active iter); cen t1<=50: [0,t1-1], s=1-sum;
//      cen t1>50: [t1,99] direct. Same granules as R6.
//  - ALL 13x64 row loads independent -> 2 dependent stages per wave
//    (vs ~15 grid-stride trips x 2 stages in R6)
//  - logf once, all 64 lanes useful (vs 16/64 in R6)
//  - 4096 blocks = 16384 waves >= 15625 row-batches: one batch per wave.

#define HSL_EPS 1e-10f
#define NBLK 4096

__global__ __launch_bounds__(256, 8) void hsl_main(
    const float* __restrict__ preds,
    const int*   __restrict__ labs,
    const int*   __restrict__ cen,
    double*       __restrict__ bsums,  // [4][NBLK] per-block partials
    unsigned int* __restrict__ bcnts,  // [4][NBLK]
    long long N)
{
    const long long R = 2LL * N;
    const int lane = threadIdx.x & 63;
    const long long w0 = ((long long)blockIdx.x * blockDim.x + threadIdx.x) >> 6;
    const long long nw = ((long long)gridDim.x * blockDim.x) >> 6;

    double usum[2] = {0.0, 0.0};
    double csum[2] = {0.0, 0.0};
    unsigned int ucnt[2] = {0u, 0u};
    unsigned int ccnt[2] = {0u, 0u};

    for (long long rb = w0 * 64; rb < R; rb += nw * 64) {
        const long long r = rb + lane;           // lane's own row
        const bool valid = (r < R);
        const long long rc = valid ? r : (R - 1);

        // ---- descriptors: fully-coalesced (64 consecutive ints per wave) ----
        const int m    = (rc >= N) ? 1 : 0;
        const int c    = cen[rc];
        const int lab  = labs[rc];
        const int lab0 = m ? labs[rc - N] : lab; // mod0: labs0 == lab (skip load)
        const int t1   = lab0 + 1;               // in [1,100]

        // ---- unified per-lane [lo,hi] + flip ----
        int lo, hi; bool flip = false;
        if (c == 0)        { lo = lab; hi = lab; }
        else if (t1 <= 50) { lo = 0;   hi = t1 - 1; flip = true; }  // s = 1 - prefix
        else               { lo = t1;  hi = 99; }                   // direct suffix
        const int s4 = lo >> 2;
        const int e4 = hi >> 2;                  // e4 - s4 <= 12 in all cases

        const float4* rowp4 = (const float4*)(preds + rc * 100);

        // ---- <=13 predicated float4 gathers, all independent ----
        float acc = 0.0f;
        #pragma unroll
        for (int k = 0; k < 13; ++k) {
            const int f4 = s4 + k;
            if (f4 <= e4) {                      // exec-masked: no mem request
                const float4 v = rowp4[f4];
                const int j0 = 4 * f4;
                acc += (j0     >= lo && j0     <= hi) ? v.x : 0.0f;
                acc += (j0 + 1 >= lo && j0 + 1 <= hi) ? v.y : 0.0f;
                acc += (j0 + 2 >= lo && j0 + 2 <= hi) ? v.z : 0.0f;
                acc += (j0 + 3 >= lo && j0 + 3 <= hi) ? v.w : 0.0f;
            }
        }

        if (valid) {
            const float s = flip ? (1.0f - acc) : acc;
            const double lg = (double)logf(s + HSL_EPS);  // all 64 lanes useful
            if (c == 0) { usum[m] += lg; ucnt[m]++; }
            else        { csum[m] += lg; ccnt[m]++; }
        }
    }

    // ---- wave shuffle reduction -> block LDS -> one plain store per block ----
    #pragma unroll
    for (int off = 32; off > 0; off >>= 1) {
        usum[0] += __shfl_down(usum[0], off, 64);
        csum[0] += __shfl_down(csum[0], off, 64);
        usum[1] += __shfl_down(usum[1], off, 64);
        csum[1] += __shfl_down(csum[1], off, 64);
        ucnt[0] += __shfl_down(ucnt[0], off, 64);
        ccnt[0] += __shfl_down(ccnt[0], off, 64);
        ucnt[1] += __shfl_down(ucnt[1], off, 64);
        ccnt[1] += __shfl_down(ccnt[1], off, 64);
    }

    __shared__ double sh_sums[4][4];
    __shared__ unsigned int sh_cnts[4][4];
    const int waveInBlk = threadIdx.x >> 6;
    if (lane == 0) {
        sh_sums[waveInBlk][0] = usum[0]; sh_sums[waveInBlk][1] = csum[0];
        sh_sums[waveInBlk][2] = usum[1]; sh_sums[waveInBlk][3] = csum[1];
        sh_cnts[waveInBlk][0] = ucnt[0]; sh_cnts[waveInBlk][1] = ccnt[0];
        sh_cnts[waveInBlk][2] = ucnt[1]; sh_cnts[waveInBlk][3] = ccnt[1];
    }
    __syncthreads();
    if (threadIdx.x < 4) {
        const int slot = threadIdx.x;
        double s = 0.0; unsigned int k = 0u;
        for (int w = 0; w < 4; ++w) { s += sh_sums[w][slot]; k += sh_cnts[w][slot]; }
        bsums[slot * NBLK + blockIdx.x] = s;
        bcnts[slot * NBLK + blockIdx.x] = k;
    }
}

__global__ __launch_bounds__(256) void hsl_final(
    const double* __restrict__ bsums,
    const unsigned int* __restrict__ bcnts,
    float* __restrict__ out, long long N, int nblk)
{
    double s[4] = {0.0, 0.0, 0.0, 0.0};
    double kc[4] = {0.0, 0.0, 0.0, 0.0};
    for (int b = threadIdx.x; b < nblk; b += 256) {
        #pragma unroll
        for (int slot = 0; slot < 4; ++slot) {
            s[slot]  += bsums[slot * nblk + b];
            kc[slot] += (double)bcnts[slot * nblk + b];
        }
    }

    #pragma unroll
    for (int off = 32; off > 0; off >>= 1) {
        #pragma unroll
        for (int slot = 0; slot < 4; ++slot) {
            s[slot]  += __shfl_down(s[slot],  off, 64);
            kc[slot] += __shfl_down(kc[slot], off, 64);
        }
    }

    __shared__ double sh[4][8];
    const int waveInBlk = threadIdx.x >> 6;
    const int lane = threadIdx.x & 63;
    if (lane == 0) {
        #pragma unroll
        for (int slot = 0; slot < 4; ++slot) {
            sh[waveInBlk][slot]     = s[slot];
            sh[waveInBlk][4 + slot] = kc[slot];
        }
    }
    __syncthreads();
    if (threadIdx.x == 0) {
        double fs[4], fk[4];
        #pragma unroll
        for (int slot = 0; slot < 4; ++slot) {
            fs[slot] = sh[0][slot] + sh[1][slot] + sh[2][slot] + sh[3][slot];
            fk[slot] = sh[0][4+slot] + sh[1][4+slot] + sh[2][4+slot] + sh[3][4+slot];
        }
        float total = 0.0f;
        const float n = (float)N;
        for (int m = 0; m < 2; ++m) {
            const float nu = (float)fk[2 * m + 0];
            const float nc = (float)fk[2 * m + 1];
            const float us = (float)fs[2 * m + 0];
            const float cs = (float)fs[2 * m + 1];
            const float uncen_loss = -us / fmaxf(1.0f, nu);
            const float cen_loss   = -cs / fmaxf(1.0f, nc);
            total += (nu / n) * uncen_loss + (nc / n) * cen_loss * 0.5f;
        }
        out[0] = total;
    }
}

extern "C" void kernel_launch(void* const* d_in, const int* in_sizes, int n_in,
                              void* d_out, int out_size, void* d_ws, size_t ws_size,
                              hipStream_t stream)
{
    const float* preds = (const float*)d_in[0];
    const int*   labs  = (const int*)d_in[1];
    const int*   cen   = (const int*)d_in[2];
    float* out = (float*)d_out;

    const long long N = (long long)(in_sizes[1] / 2);   // labs flat = 2*N; B=100 hardcoded

    double*       bsums = (double*)d_ws;
    unsigned int* bcnts = (unsigned int*)((char*)d_ws + (size_t)4 * NBLK * sizeof(double));

    hsl_main<<<NBLK, 256, 0, stream>>>(preds, labs, cen, bsums, bcnts, N);
    hsl_final<<<1, 256, 0, stream>>>(bsums, bcnts, out, N, NBLK);
}